// Round 3
// baseline (6096.730 us; speedup 1.0000x reference)
//
#include <hip/hip_runtime.h>
#include <stdint.h>

#define T_LEN 512
#define BATCH 128
#define HID 256
#define MROWS (T_LEN*BATCH)   // 65536
#define KIN 512

typedef __attribute__((ext_vector_type(8))) short short8;
typedef __attribute__((ext_vector_type(4))) float f32x4;
typedef __attribute__((ext_vector_type(4))) unsigned short u16x4;

static __device__ __forceinline__ float bf2f(unsigned short u) {
  union { unsigned int u; float f; } c; c.u = ((unsigned int)u) << 16; return c.f;
}
static __device__ __forceinline__ unsigned short f2bf(float f) {
  union { float f; unsigned int u; } c; c.f = f;
  unsigned int x = c.u;
  x += 0x7fffu + ((x >> 16) & 1u);   // RNE
  return (unsigned short)(x >> 16);
}
static __device__ __forceinline__ void gload_lds16(const void* g, void* l) {
  __builtin_amdgcn_global_load_lds((const __attribute__((address_space(1))) unsigned int*)g,
                                   (__attribute__((address_space(3))) unsigned int*)l,
                                   16, 0, 0);
}
static __device__ __forceinline__ float fast_sigm(float x) {
  return __builtin_amdgcn_rcpf(1.0f + __expf(-x));
}
static __device__ __forceinline__ float fast_tanh(float x) {
  float e = __expf(2.0f * x);
  return 1.0f - 2.0f * __builtin_amdgcn_rcpf(1.0f + e);
}

// ---------------- fp32 -> bf16 conversion (n % 4 == 0) ----------------
__global__ void cvt_bf16(const float* __restrict__ in, unsigned short* __restrict__ out, long n) {
  long i = ((long)blockIdx.x * blockDim.x + threadIdx.x) * 4;
  const long stride = (long)gridDim.x * blockDim.x * 4;
  for (; i < n; i += stride) {
    f32x4 v = *(const f32x4*)(in + i);
    u16x4 o;
    o[0] = f2bf(v[0]); o[1] = f2bf(v[1]); o[2] = f2bf(v[2]); o[3] = f2bf(v[3]);
    *(u16x4*)(out + i) = o;
  }
}

// ---------------- input GEMM: gate_x = A[65536,512] * W[1536,512]^T + bias ----------------
__global__ __launch_bounds__(256) void gemm_gx(
    const unsigned short* __restrict__ A,
    const unsigned short* __restrict__ Bw,
    const float* __restrict__ bih,
    const float* __restrict__ bhh,
    unsigned short* __restrict__ gx)
{
  __shared__ unsigned short As[128*64];
  __shared__ unsigned short Bs[128*64];
  const int tid = threadIdx.x, lane = tid & 63, wv = tid >> 6;
  const int bid = blockIdx.x;
  const int nt = bid % 12; const long mt = bid / 12;
  const long m0 = mt * 128; const int n0 = nt * 128;
  const int wm = wv >> 1, wn = wv & 1;
  const int r8 = lane >> 3, c8 = lane & 7;

  f32x4 acc[4][4];
  #pragma unroll
  for (int i = 0; i < 4; ++i) {
    #pragma unroll
    for (int j = 0; j < 4; ++j) acc[i][j] = (f32x4)0.0f;
  }

  for (int kt = 0; kt < 8; ++kt) {
    const int kb = kt * 64;
    #pragma unroll
    for (int c = 0; c < 4; ++c) {
      const int rr = c*32 + wv*8;
      gload_lds16(A  + (m0 + rr + r8) * (long)KIN + kb + c8*8, &As[rr*64]);
      gload_lds16(Bw + (long)(n0 + rr + r8) * KIN + kb + c8*8, &Bs[rr*64]);
    }
    __syncthreads();
    #pragma unroll
    for (int kk = 0; kk < 2; ++kk) {
      short8 af[4], bfr[4];
      #pragma unroll
      for (int i = 0; i < 4; ++i)
        af[i] = *(const short8*)&As[(wm*64 + i*16 + (lane&15))*64 + kk*32 + (lane>>4)*8];
      #pragma unroll
      for (int j = 0; j < 4; ++j)
        bfr[j] = *(const short8*)&Bs[(wn*64 + j*16 + (lane&15))*64 + kk*32 + (lane>>4)*8];
      #pragma unroll
      for (int i = 0; i < 4; ++i) {
        #pragma unroll
        for (int j = 0; j < 4; ++j)
          acc[i][j] = __builtin_amdgcn_mfma_f32_16x16x32_bf16(af[i], bfr[j], acc[i][j], 0, 0, 0);
      }
    }
    __syncthreads();
  }

  const int d = (n0 >= 768) ? 1 : 0;
  #pragma unroll
  for (int j = 0; j < 4; ++j) {
    const int n = n0 + wn*64 + j*16 + (lane & 15);
    const int g = n - d*768;
    const float bias = bih[n] + ((g < 512) ? bhh[n] : 0.0f);
    #pragma unroll
    for (int i = 0; i < 4; ++i) {
      const long row = m0 + wm*64 + i*16 + (lane >> 4)*4;
      unsigned short* op = gx + ((long)d*MROWS + row)*768 + g;
      #pragma unroll
      for (int r = 0; r < 4; ++r)
        op[(long)r*768] = f2bf(acc[i][j][r] + bias);
    }
  }
}

// ---------------- recurrent scan: fused gates on MFMA accumulators ----------------
// 16 WGs (dir = blk>>3, batch slice of 16 = blk&7), 512 threads (8 waves).
// launch_bounds(512,2): only 2 waves/SIMD ever resident -> allow the full
// 256-reg combined budget so the 192-VGPR stationary weight array feeds MFMA
// directly (r2's 128-VGPR cap forced ~192 accvgpr_read copies per wave per step).
__global__ __launch_bounds__(512, 2) void gru_rec(
    const unsigned short* __restrict__ gx,    // [2][65536][768] bf16
    const unsigned short* __restrict__ Whh,   // [2][768][256] bf16 (this layer)
    const float* __restrict__ bhh,            // [2][768] fp32 (this layer)
    const float* __restrict__ h0,             // [6][128][256]
    unsigned short* __restrict__ act,         // [65536][512] bf16 (layer output)
    float* __restrict__ hOut,                 // d_out [6][128][256]
    const int layer)
{
  __shared__ unsigned short hbuf[2][4096];    // [buf][ (j>>3)*128 + col*8 + (j&7) ]
  const int tid = threadIdx.x, lane = tid & 63, wv = tid >> 6;
  const int d = blockIdx.x >> 3, s = blockIdx.x & 7;
  const int g = lane >> 4, c = lane & 15;
  const int mb = s*16 + c;

  // --- stationary weights: rt = gate*2+q -> rows gate*256 + wv*32 + q*16 ---
  short8 a[6][8];
  {
    const unsigned short* wb = Whh + (long)d*768*256;
    #pragma unroll
    for (int rt = 0; rt < 6; ++rt) {
      const int rowb = (rt >> 1)*256 + wv*32 + (rt & 1)*16;
      #pragma unroll
      for (int kf = 0; kf < 8; ++kf)
        a[rt][kf] = *(const short8*)&wb[(rowb + c)*256 + kf*32 + g*8];
    }
  }

  const int jb0 = wv*32 + g*4;                 // q=0 j-base; q=1 adds +16
  const int woff0 = (wv*4 + (g>>1))*128 + c*8 + (g&1)*4;   // hbuf idx for q=0
  const int woff1 = woff0 + 2*128;                          // q=1 (j+16 -> group+2)

  // --- init h (bf16 regs + LDS buf 0) ---
  u16x4 hq[2];
  {
    const float* hp = h0 + ((long)(layer*2 + d)*BATCH + mb)*HID + jb0;
    #pragma unroll
    for (int q = 0; q < 2; ++q) {
      #pragma unroll
      for (int i = 0; i < 4; ++i) hq[q][i] = f2bf(hp[q*16 + i]);
    }
    *(u16x4*)&hbuf[0][woff0] = hq[0];
    *(u16x4*)&hbuf[0][woff1] = hq[1];
  }
  u16x4 bnb[2];   // n-gate b_hh, packed bf16
  {
    const float* bp = bhh + d*768 + 512 + jb0;
    #pragma unroll
    for (int q = 0; q < 2; ++q)
      #pragma unroll
      for (int i = 0; i < 4; ++i) bnb[q][i] = f2bf(bp[q*16 + i]);
  }

  // --- running pointers ---
  const long t0 = d ? 511 : 0;
  const long dgx = d ? -(long)(BATCH*768) : (long)(BATCH*768);
  const long dac = d ? -(long)(BATCH*512) : (long)(BATCH*512);
  const unsigned short* pg = gx + ((long)d*MROWS + t0*BATCH + mb)*768 + jb0;
  unsigned short* pa = act + (t0*BATCH + mb)*512 + d*256 + jb0;

  asm volatile("s_waitcnt lgkmcnt(0)\n\ts_barrier" ::: "memory");

  int p = 0;
  #pragma unroll 1
  for (int t = 0; t < 512; ++t) {
    // 1. gate_x loads for THIS step (used only after the MFMA phase -> latency
    //    hides under ~1.9k cycles of MFMA issue; barrier never drains vmcnt)
    u16x4 cx[3][2];
    #pragma unroll
    for (int gt = 0; gt < 3; ++gt) {
      #pragma unroll
      for (int q = 0; q < 2; ++q)
        cx[gt][q] = *(const u16x4*)(pg + gt*256 + q*16);
    }

    // 2. matvec: acc[rt] = W_hh[rows(rt)] * h
    f32x4 acc[6];
    #pragma unroll
    for (int rt = 0; rt < 6; ++rt) acc[rt] = (f32x4)0.0f;
    __builtin_amdgcn_s_setprio(1);
    {
      const unsigned short* hb = &hbuf[p][0];
      #pragma unroll
      for (int kf = 0; kf < 8; ++kf) {
        short8 b = *(const short8*)&hb[(kf*64 + lane)*8];
        #pragma unroll
        for (int rt = 0; rt < 6; ++rt)
          acc[rt] = __builtin_amdgcn_mfma_f32_16x16x32_bf16(a[rt][kf], b, acc[rt], 0, 0, 0);
      }
    }
    __builtin_amdgcn_s_setprio(0);

    // 3. gates directly on accumulators
    #pragma unroll
    for (int q = 0; q < 2; ++q) {
      u16x4 hn;
      #pragma unroll
      for (int i = 0; i < 4; ++i) {
        const float r = fast_sigm(bf2f(cx[0][q][i]) + acc[0*2+q][i]);
        const float z = fast_sigm(bf2f(cx[1][q][i]) + acc[1*2+q][i]);
        const float nn = fast_tanh(bf2f(cx[2][q][i]) + r * (acc[2*2+q][i] + bf2f(bnb[q][i])));
        const float hf = nn + z * (bf2f(hq[q][i]) - nn);
        hn[i] = f2bf(hf);
      }
      hq[q] = hn;
    }

    // 4. publish h_{t+1}: LDS (next buffer) + layer output
    *(u16x4*)&hbuf[p^1][woff0] = hq[0];
    *(u16x4*)&hbuf[p^1][woff1] = hq[1];
    *(u16x4*)(pa)      = hq[0];
    *(u16x4*)(pa + 16) = hq[1];

    pg += dgx; pa += dac; p ^= 1;
    asm volatile("s_waitcnt lgkmcnt(0)\n\ts_barrier" ::: "memory");
  }

  // epilogue: final hidden state (from the bf16 state, same values gates used)
  {
    float* po = hOut + ((long)(layer*2 + d)*BATCH + mb)*HID + jb0;
    #pragma unroll
    for (int q = 0; q < 2; ++q)
      #pragma unroll
      for (int i = 0; i < 4; ++i) po[q*16 + i] = bf2f(hq[q][i]);
  }
}

extern "C" void kernel_launch(void* const* d_in, const int* in_sizes, int n_in,
                              void* d_out, int out_size, void* d_ws, size_t ws_size,
                              hipStream_t stream) {
  const float* x   = (const float*)d_in[0];
  const float* h0  = (const float*)d_in[1];
  const float* wih = (const float*)d_in[2];
  const float* whh = (const float*)d_in[3];
  const float* bih = (const float*)d_in[4];
  const float* bhh = (const float*)d_in[5];
  float* out = (float*)d_out;
  char* ws = (char*)d_ws;
  unsigned short* actA = (unsigned short*)ws;                    //  67,108,864 B
  unsigned short* actB = (unsigned short*)(ws + 67108864);       //  67,108,864 B
  unsigned short* gxb  = (unsigned short*)(ws + 134217728);      // 201,326,592 B
  unsigned short* wihb = (unsigned short*)(ws + 335544320);      //   4,718,592 B
  unsigned short* whhb = (unsigned short*)(ws + 340262912);      //   2,359,296 B
  if (ws_size < 342622208ULL) return;

  hipLaunchKernelGGL(cvt_bf16, dim3(2048), dim3(256), 0, stream, x,   actA, (long)33554432);
  hipLaunchKernelGGL(cvt_bf16, dim3(512),  dim3(256), 0, stream, wih, wihb, (long)2359296);
  hipLaunchKernelGGL(cvt_bf16, dim3(256),  dim3(256), 0, stream, whh, whhb, (long)1179648);

  for (int l = 0; l < 3; ++l) {
    const unsigned short* Ain = (l == 1) ? actB : actA;
    unsigned short* Aout      = (l == 1) ? actA : actB;
    hipLaunchKernelGGL(gemm_gx, dim3(6144), dim3(256), 0, stream,
                       Ain, wihb + (long)l*1536*512, bih + l*1536, bhh + l*1536, gxb);
    hipLaunchKernelGGL(gru_rec, dim3(16), dim3(512), 0, stream,
                       gxb, whhb + (long)l*2*768*256, bhh + l*1536, h0, Aout, out, l);
  }
}

// Round 4
// 5587.003 us; speedup vs baseline: 1.0912x; 1.0912x over previous
//
#include <hip/hip_runtime.h>
#include <stdint.h>

#define T_LEN 512
#define BATCH 128
#define HID 256
#define MROWS (T_LEN*BATCH)   // 65536
#define KIN 512

typedef __attribute__((ext_vector_type(8))) short short8;
typedef __attribute__((ext_vector_type(4))) float f32x4;
typedef __attribute__((ext_vector_type(4))) unsigned short u16x4;

static __device__ __forceinline__ float bf2f(unsigned short u) {
  union { unsigned int u; float f; } c; c.u = ((unsigned int)u) << 16; return c.f;
}
static __device__ __forceinline__ unsigned short f2bf(float f) {
  union { float f; unsigned int u; } c; c.f = f;
  unsigned int x = c.u;
  x += 0x7fffu + ((x >> 16) & 1u);   // RNE
  return (unsigned short)(x >> 16);
}
static __device__ __forceinline__ void gload_lds16(const void* g, void* l) {
  __builtin_amdgcn_global_load_lds((const __attribute__((address_space(1))) unsigned int*)g,
                                   (__attribute__((address_space(3))) unsigned int*)l,
                                   16, 0, 0);
}
static __device__ __forceinline__ float fast_sigm(float x) {
  return __builtin_amdgcn_rcpf(1.0f + __expf(-x));
}
static __device__ __forceinline__ float fast_tanh(float x) {
  float e = __expf(2.0f * x);
  return 1.0f - 2.0f * __builtin_amdgcn_rcpf(1.0f + e);
}

// ---------------- fp32 -> bf16 conversion (n % 4 == 0) ----------------
__global__ void cvt_bf16(const float* __restrict__ in, unsigned short* __restrict__ out, long n) {
  long i = ((long)blockIdx.x * blockDim.x + threadIdx.x) * 4;
  const long stride = (long)gridDim.x * blockDim.x * 4;
  for (; i < n; i += stride) {
    f32x4 v = *(const f32x4*)(in + i);
    u16x4 o;
    o[0] = f2bf(v[0]); o[1] = f2bf(v[1]); o[2] = f2bf(v[2]); o[3] = f2bf(v[3]);
    *(u16x4*)(out + i) = o;
  }
}

// ---------------- input GEMM: gate_x = A[65536,512] * W[1536,512]^T + bias ----------------
__global__ __launch_bounds__(256) void gemm_gx(
    const unsigned short* __restrict__ A,
    const unsigned short* __restrict__ Bw,
    const float* __restrict__ bih,
    const float* __restrict__ bhh,
    unsigned short* __restrict__ gx)
{
  __shared__ unsigned short As[128*64];
  __shared__ unsigned short Bs[128*64];
  const int tid = threadIdx.x, lane = tid & 63, wv = tid >> 6;
  const int bid = blockIdx.x;
  const int nt = bid % 12; const long mt = bid / 12;
  const long m0 = mt * 128; const int n0 = nt * 128;
  const int wm = wv >> 1, wn = wv & 1;
  const int r8 = lane >> 3, c8 = lane & 7;

  f32x4 acc[4][4];
  #pragma unroll
  for (int i = 0; i < 4; ++i) {
    #pragma unroll
    for (int j = 0; j < 4; ++j) acc[i][j] = (f32x4)0.0f;
  }

  for (int kt = 0; kt < 8; ++kt) {
    const int kb = kt * 64;
    #pragma unroll
    for (int c = 0; c < 4; ++c) {
      const int rr = c*32 + wv*8;
      gload_lds16(A  + (m0 + rr + r8) * (long)KIN + kb + c8*8, &As[rr*64]);
      gload_lds16(Bw + (long)(n0 + rr + r8) * KIN + kb + c8*8, &Bs[rr*64]);
    }
    __syncthreads();
    #pragma unroll
    for (int kk = 0; kk < 2; ++kk) {
      short8 af[4], bfr[4];
      #pragma unroll
      for (int i = 0; i < 4; ++i)
        af[i] = *(const short8*)&As[(wm*64 + i*16 + (lane&15))*64 + kk*32 + (lane>>4)*8];
      #pragma unroll
      for (int j = 0; j < 4; ++j)
        bfr[j] = *(const short8*)&Bs[(wn*64 + j*16 + (lane&15))*64 + kk*32 + (lane>>4)*8];
      #pragma unroll
      for (int i = 0; i < 4; ++i) {
        #pragma unroll
        for (int j = 0; j < 4; ++j)
          acc[i][j] = __builtin_amdgcn_mfma_f32_16x16x32_bf16(af[i], bfr[j], acc[i][j], 0, 0, 0);
      }
    }
    __syncthreads();
  }

  const int d = (n0 >= 768) ? 1 : 0;
  #pragma unroll
  for (int j = 0; j < 4; ++j) {
    const int n = n0 + wn*64 + j*16 + (lane & 15);
    const int g = n - d*768;
    const float bias = bih[n] + ((g < 512) ? bhh[n] : 0.0f);
    #pragma unroll
    for (int i = 0; i < 4; ++i) {
      const long row = m0 + wm*64 + i*16 + (lane >> 4)*4;
      unsigned short* op = gx + ((long)d*MROWS + row)*768 + g;
      #pragma unroll
      for (int r = 0; r < 4; ++r)
        op[(long)r*768] = f2bf(acc[i][j][r] + bias);
    }
  }
}

// ---------------- recurrent scan: 4 waves, 1 wave/SIMD, 512-reg budget ----------------
// 16 WGs (dir = blk>>3, batch slice of 16 = blk&7), 256 threads (4 waves).
// Wave v owns 192 W_hh rows: {gate*256 + v*64 + jt*16} for gate 0..2, jt 0..3
// = 12 row-tiles = 384 VGPRs of stationary weights. 1 wave/SIMD -> per-wave
// budget is the full 512-reg unified file (r2/r3's 8-wave layout only had 256,
// forcing the compiler to shuffle weights through AGPR copies ~190 VALU/step).
// Gates run on MFMA accumulators (same-j-in-all-gates tiling). n-gate bias
// pre-loaded into the accumulator from LDS. gx prefetched one step ahead with
// compile-time cx/nx ping-pong (x2 unroll). One s_barrier/step, lgkm-only wait.
__global__ __launch_bounds__(256, 1) void gru_rec(
    const unsigned short* __restrict__ gx,    // [2][65536][768] bf16
    const unsigned short* __restrict__ Whh,   // [2][768][256] bf16 (this layer)
    const float* __restrict__ bhh,            // [2][768] fp32 (this layer)
    const float* __restrict__ h0,             // [6][128][256]
    unsigned short* __restrict__ act,         // [65536][512] bf16 (layer output)
    float* __restrict__ hOut,                 // d_out [6][128][256]
    const int layer)
{
  __shared__ unsigned short hbuf[2][4096];    // [buf][ (j>>3)*128 + col*8 + (j&7) ]
  __shared__ float bnl[256];                  // n-gate b_hh for this dir
  const int tid = threadIdx.x, lane = tid & 63, wv = tid >> 6;  // wv 0..3
  const int d = blockIdx.x >> 3, s = blockIdx.x & 7;
  const int g4 = lane >> 4, c = lane & 15;
  const int mb = s*16 + c;

  // --- stationary weights: rt = gate*4+jt -> rows gate*256 + wv*64 + jt*16 ---
  short8 a[12][8];
  {
    const unsigned short* wb = Whh + (long)d*768*256;
    #pragma unroll
    for (int rt = 0; rt < 12; ++rt) {
      const int row = (rt>>2)*256 + wv*64 + (rt&3)*16 + c;
      #pragma unroll
      for (int kf = 0; kf < 8; ++kf)
        a[rt][kf] = *(const short8*)&wb[row*256 + kf*32 + g4*8];
    }
  }

  bnl[tid] = bhh[d*768 + 512 + tid];

  // thread's own j-elems: j = wv*64 + jt*16 + g4*4 + i  (i=0..3), col = c
  int woff[4];
  #pragma unroll
  for (int jt = 0; jt < 4; ++jt)
    woff[jt] = (wv*8 + jt*2 + (g4>>1))*128 + c*8 + (g4&1)*4;

  // --- init h into hbuf[0] ---
  {
    const float* hp = h0 + ((long)(layer*2 + d)*BATCH + mb)*HID + wv*64 + g4*4;
    #pragma unroll
    for (int jt = 0; jt < 4; ++jt) {
      u16x4 hv;
      #pragma unroll
      for (int i = 0; i < 4; ++i) hv[i] = f2bf(hp[jt*16 + i]);
      *(u16x4*)&hbuf[0][woff[jt]] = hv;
    }
  }

  // --- running pointers (pre-offset to this thread's j-slice) ---
  const long t0 = d ? 511 : 0;
  const long dgx = d ? -(long)(BATCH*768) : (long)(BATCH*768);
  const long dac = d ? -(long)(BATCH*512) : (long)(BATCH*512);
  const unsigned short* pg = gx + ((long)d*MROWS + t0*BATCH + mb)*768 + wv*64 + g4*4;
  unsigned short* pa = act + (t0*BATCH + mb)*512 + d*256 + wv*64 + g4*4;

  // --- prologue: gx for t=0 ---
  u16x4 cxA[3][4], cxB[3][4];
  #pragma unroll
  for (int gt = 0; gt < 3; ++gt)
    #pragma unroll
    for (int jt = 0; jt < 4; ++jt)
      cxA[gt][jt] = *(const u16x4*)(pg + gt*256 + jt*16);
  pg += dgx;

  __syncthreads();

// One GRU step. P = hbuf parity (compile-time), CX = this step's gate_x,
// NX = next step's gate_x (issued here, consumed next step -> HBM latency
// hides under a full step; barrier never drains vmcnt).
#define STEP(P, CX, NX)                                                       \
  {                                                                           \
    _Pragma("unroll") for (int gt = 0; gt < 3; ++gt)                          \
      _Pragma("unroll") for (int jt = 0; jt < 4; ++jt)                        \
        NX[gt][jt] = *(const u16x4*)(pg + gt*256 + jt*16);                    \
    f32x4 acc[12];                                                            \
    _Pragma("unroll") for (int rt = 0; rt < 8; ++rt) acc[rt] = (f32x4)0.0f;   \
    _Pragma("unroll") for (int jt = 0; jt < 4; ++jt)                          \
      acc[8+jt] = *(const f32x4*)&bnl[wv*64 + jt*16 + g4*4];                  \
    u16x4 hold[4];                                                            \
    _Pragma("unroll") for (int jt = 0; jt < 4; ++jt)                          \
      hold[jt] = *(const u16x4*)&hbuf[P][woff[jt]];                           \
    _Pragma("unroll") for (int kf = 0; kf < 8; ++kf) {                        \
      short8 b = *(const short8*)&hbuf[P][(kf*64 + lane)*8];                  \
      _Pragma("unroll") for (int rt = 0; rt < 12; ++rt)                       \
        acc[rt] = __builtin_amdgcn_mfma_f32_16x16x32_bf16(a[rt][kf], b, acc[rt], 0, 0, 0); \
    }                                                                         \
    _Pragma("unroll") for (int jt = 0; jt < 4; ++jt) {                        \
      u16x4 hn;                                                               \
      _Pragma("unroll") for (int i = 0; i < 4; ++i) {                         \
        const float r = fast_sigm(bf2f(CX[0][jt][i]) + acc[jt][i]);           \
        const float z = fast_sigm(bf2f(CX[1][jt][i]) + acc[4+jt][i]);         \
        const float nn = fast_tanh(bf2f(CX[2][jt][i]) + r * acc[8+jt][i]);    \
        const float hf = nn + z * (bf2f(hold[jt][i]) - nn);                   \
        hn[i] = f2bf(hf);                                                     \
      }                                                                       \
      *(u16x4*)&hbuf[P^1][woff[jt]] = hn;                                     \
      *(u16x4*)(pa + jt*16) = hn;                                             \
    }                                                                         \
    pg += dgx; pa += dac;                                                     \
    asm volatile("s_waitcnt lgkmcnt(0)\n\ts_barrier" ::: "memory");           \
  }

  #pragma unroll 1
  for (int t2 = 0; t2 < 256; ++t2) {
    STEP(0, cxA, cxB)
    STEP(1, cxB, cxA)
  }
#undef STEP

  // epilogue: final hidden state is in hbuf[0] (512 toggles)
  {
    float* po = hOut + ((long)(layer*2 + d)*BATCH + mb)*HID + wv*64 + g4*4;
    #pragma unroll
    for (int jt = 0; jt < 4; ++jt) {
      u16x4 hv = *(const u16x4*)&hbuf[0][woff[jt]];
      #pragma unroll
      for (int i = 0; i < 4; ++i) po[jt*16 + i] = bf2f(hv[i]);
    }
  }
}

extern "C" void kernel_launch(void* const* d_in, const int* in_sizes, int n_in,
                              void* d_out, int out_size, void* d_ws, size_t ws_size,
                              hipStream_t stream) {
  const float* x   = (const float*)d_in[0];
  const float* h0  = (const float*)d_in[1];
  const float* wih = (const float*)d_in[2];
  const float* whh = (const float*)d_in[3];
  const float* bih = (const float*)d_in[4];
  const float* bhh = (const float*)d_in[5];
  float* out = (float*)d_out;
  char* ws = (char*)d_ws;
  unsigned short* actA = (unsigned short*)ws;                    //  67,108,864 B
  unsigned short* actB = (unsigned short*)(ws + 67108864);       //  67,108,864 B
  unsigned short* gxb  = (unsigned short*)(ws + 134217728);      // 201,326,592 B
  unsigned short* wihb = (unsigned short*)(ws + 335544320);      //   4,718,592 B
  unsigned short* whhb = (unsigned short*)(ws + 340262912);      //   2,359,296 B
  if (ws_size < 342622208ULL) return;

  hipLaunchKernelGGL(cvt_bf16, dim3(2048), dim3(256), 0, stream, x,   actA, (long)33554432);
  hipLaunchKernelGGL(cvt_bf16, dim3(512),  dim3(256), 0, stream, wih, wihb, (long)2359296);
  hipLaunchKernelGGL(cvt_bf16, dim3(256),  dim3(256), 0, stream, whh, whhb, (long)1179648);

  for (int l = 0; l < 3; ++l) {
    const unsigned short* Ain = (l == 1) ? actB : actA;
    unsigned short* Aout      = (l == 1) ? actA : actB;
    hipLaunchKernelGGL(gemm_gx, dim3(6144), dim3(256), 0, stream,
                       Ain, wihb + (long)l*1536*512, bih + l*1536, bhh + l*1536, gxb);
    hipLaunchKernelGGL(gru_rec, dim3(16), dim3(256), 0, stream,
                       gxb, whhb + (long)l*2*768*256, bhh + l*1536, h0, Aout, out, l);
  }
}

// Round 5
// 4358.397 us; speedup vs baseline: 1.3988x; 1.2819x over previous
//
#include <hip/hip_runtime.h>
#include <stdint.h>

#define T_LEN 512
#define BATCH 128
#define HID 256
#define MROWS (T_LEN*BATCH)   // 65536
#define KIN 512

typedef __attribute__((ext_vector_type(8))) short short8;
typedef __attribute__((ext_vector_type(4))) float f32x4;
typedef __attribute__((ext_vector_type(4))) unsigned short u16x4;

static __device__ __forceinline__ float bf2f(unsigned short u) {
  union { unsigned int u; float f; } c; c.u = ((unsigned int)u) << 16; return c.f;
}
static __device__ __forceinline__ unsigned short f2bf(float f) {
  union { float f; unsigned int u; } c; c.f = f;
  unsigned int x = c.u;
  x += 0x7fffu + ((x >> 16) & 1u);   // RNE
  return (unsigned short)(x >> 16);
}
static __device__ __forceinline__ void gload_lds16(const void* g, void* l) {
  __builtin_amdgcn_global_load_lds((const __attribute__((address_space(1))) unsigned int*)g,
                                   (__attribute__((address_space(3))) unsigned int*)l,
                                   16, 0, 0);
}
static __device__ __forceinline__ float fast_sigm(float x) {
  return __builtin_amdgcn_rcpf(1.0f + __expf(-x));
}
static __device__ __forceinline__ float fast_tanh(float x) {
  float e = __expf(2.0f * x);
  return 1.0f - 2.0f * __builtin_amdgcn_rcpf(1.0f + e);
}

// MFMA with A-operand pinned to AGPR (no accvgpr_read copies) / to arch VGPR.
#define MFMA_AG(D, W, B) \
  asm("v_mfma_f32_16x16x32_bf16 %0, %1, %2, %0" : "+v"(D) : "a"(W), "v"(B))
#define MFMA_VG(D, W, B) \
  asm("v_mfma_f32_16x16x32_bf16 %0, %1, %2, %0" : "+v"(D) : "v"(W), "v"(B))

// ---------------- fp32 -> bf16 conversion (n % 4 == 0) ----------------
__global__ void cvt_bf16(const float* __restrict__ in, unsigned short* __restrict__ out, long n) {
  long i = ((long)blockIdx.x * blockDim.x + threadIdx.x) * 4;
  const long stride = (long)gridDim.x * blockDim.x * 4;
  for (; i < n; i += stride) {
    f32x4 v = *(const f32x4*)(in + i);
    u16x4 o;
    o[0] = f2bf(v[0]); o[1] = f2bf(v[1]); o[2] = f2bf(v[2]); o[3] = f2bf(v[3]);
    *(u16x4*)(out + i) = o;
  }
}

// ---------------- input GEMM: gate_x = A[65536,512] * W[1536,512]^T + bias ----------------
__global__ __launch_bounds__(256) void gemm_gx(
    const unsigned short* __restrict__ A,
    const unsigned short* __restrict__ Bw,
    const float* __restrict__ bih,
    const float* __restrict__ bhh,
    unsigned short* __restrict__ gx)
{
  __shared__ unsigned short As[128*64];
  __shared__ unsigned short Bs[128*64];
  const int tid = threadIdx.x, lane = tid & 63, wv = tid >> 6;
  const int bid = blockIdx.x;
  const int nt = bid % 12; const long mt = bid / 12;
  const long m0 = mt * 128; const int n0 = nt * 128;
  const int wm = wv >> 1, wn = wv & 1;
  const int r8 = lane >> 3, c8 = lane & 7;

  f32x4 acc[4][4];
  #pragma unroll
  for (int i = 0; i < 4; ++i) {
    #pragma unroll
    for (int j = 0; j < 4; ++j) acc[i][j] = (f32x4)0.0f;
  }

  for (int kt = 0; kt < 8; ++kt) {
    const int kb = kt * 64;
    #pragma unroll
    for (int c = 0; c < 4; ++c) {
      const int rr = c*32 + wv*8;
      gload_lds16(A  + (m0 + rr + r8) * (long)KIN + kb + c8*8, &As[rr*64]);
      gload_lds16(Bw + (long)(n0 + rr + r8) * KIN + kb + c8*8, &Bs[rr*64]);
    }
    __syncthreads();
    #pragma unroll
    for (int kk = 0; kk < 2; ++kk) {
      short8 af[4], bfr[4];
      #pragma unroll
      for (int i = 0; i < 4; ++i)
        af[i] = *(const short8*)&As[(wm*64 + i*16 + (lane&15))*64 + kk*32 + (lane>>4)*8];
      #pragma unroll
      for (int j = 0; j < 4; ++j)
        bfr[j] = *(const short8*)&Bs[(wn*64 + j*16 + (lane&15))*64 + kk*32 + (lane>>4)*8];
      #pragma unroll
      for (int i = 0; i < 4; ++i) {
        #pragma unroll
        for (int j = 0; j < 4; ++j)
          acc[i][j] = __builtin_amdgcn_mfma_f32_16x16x32_bf16(af[i], bfr[j], acc[i][j], 0, 0, 0);
      }
    }
    __syncthreads();
  }

  const int d = (n0 >= 768) ? 1 : 0;
  #pragma unroll
  for (int j = 0; j < 4; ++j) {
    const int n = n0 + wn*64 + j*16 + (lane & 15);
    const int g = n - d*768;
    const float bias = bih[n] + ((g < 512) ? bhh[n] : 0.0f);
    #pragma unroll
    for (int i = 0; i < 4; ++i) {
      const long row = m0 + wm*64 + i*16 + (lane >> 4)*4;
      unsigned short* op = gx + ((long)d*MROWS + row)*768 + g;
      #pragma unroll
      for (int r = 0; r < 4; ++r)
        op[(long)r*768] = f2bf(acc[i][j][r] + bias);
    }
  }
}

// ---------------- recurrent scan: AGPR-direct weight-stationary MFMA ----------------
// 16 WGs (dir = blk>>3, batch slice of 16 = blk&7), 256 threads (4 waves, 1/SIMD).
// Wave v owns 192 W_hh rows as 12 row-tiles (3 gates x 4 j-tiles, same-j across
// gates so gates run on accumulators). 8 tiles (r,z gates; 256 regs) live in
// the AGPR file and feed MFMA A directly via inline asm "a" constraints — this
// removes the ~384 v_accvgpr_read/step that r2-r4 all paid (the builtin path
// requires VGPR A-operands). 4 tiles (n gate; 128 regs) live in arch VGPRs.
__global__ __launch_bounds__(256, 1) void gru_rec(
    const unsigned short* __restrict__ gx,    // [2][65536][768] bf16
    const unsigned short* __restrict__ Whh,   // [2][768][256] bf16 (this layer)
    const float* __restrict__ bhh,            // [2][768] fp32 (this layer)
    const float* __restrict__ h0,             // [6][128][256]
    unsigned short* __restrict__ act,         // [65536][512] bf16 (layer output)
    float* __restrict__ hOut,                 // d_out [6][128][256]
    const int layer)
{
  __shared__ unsigned short hbuf[2][4096];    // [buf][ (j>>3)*128 + col*8 + (j&7) ]
  __shared__ float bnl[256];                  // n-gate b_hh for this dir
  const int tid = threadIdx.x, lane = tid & 63, wv = tid >> 6;  // wv 0..3
  const int d = blockIdx.x >> 3, s = blockIdx.x & 7;
  const int g4 = lane >> 4, c = lane & 15;
  const int mb = s*16 + c;

  // --- stationary weights ---
  // aA[gt*4+jt] (gt=0:r, 1:z)  -> rows gt*256 + wv*64 + jt*16   (AGPR, 256 regs)
  // aV[jt]      (n gate)       -> rows 512 + wv*64 + jt*16      (VGPR, 128 regs)
  short8 aA[8][8];
  short8 aV[4][8];
  {
    const unsigned short* wb = Whh + (long)d*768*256;
    #pragma unroll
    for (int rt = 0; rt < 8; ++rt) {
      const int row = (rt>>2)*256 + wv*64 + (rt&3)*16 + c;
      #pragma unroll
      for (int kf = 0; kf < 8; ++kf)
        aA[rt][kf] = *(const short8*)&wb[row*256 + kf*32 + g4*8];
    }
    #pragma unroll
    for (int jt = 0; jt < 4; ++jt) {
      const int row = 512 + wv*64 + jt*16 + c;
      #pragma unroll
      for (int kf = 0; kf < 8; ++kf)
        aV[jt][kf] = *(const short8*)&wb[row*256 + kf*32 + g4*8];
    }
  }

  bnl[tid] = bhh[d*768 + 512 + tid];

  // thread's own j-elems: j = wv*64 + jt*16 + g4*4 + i  (i=0..3), col = c
  int woff[4];
  #pragma unroll
  for (int jt = 0; jt < 4; ++jt)
    woff[jt] = (wv*8 + jt*2 + (g4>>1))*128 + c*8 + (g4&1)*4;

  // --- init h into hbuf[0] ---
  {
    const float* hp = h0 + ((long)(layer*2 + d)*BATCH + mb)*HID + wv*64 + g4*4;
    #pragma unroll
    for (int jt = 0; jt < 4; ++jt) {
      u16x4 hv;
      #pragma unroll
      for (int i = 0; i < 4; ++i) hv[i] = f2bf(hp[jt*16 + i]);
      *(u16x4*)&hbuf[0][woff[jt]] = hv;
    }
  }

  // --- running pointers (pre-offset to this thread's j-slice) ---
  const long t0 = d ? 511 : 0;
  const long dgx = d ? -(long)(BATCH*768) : (long)(BATCH*768);
  const long dac = d ? -(long)(BATCH*512) : (long)(BATCH*512);
  const unsigned short* pg = gx + ((long)d*MROWS + t0*BATCH + mb)*768 + wv*64 + g4*4;
  unsigned short* pa = act + (t0*BATCH + mb)*512 + d*256 + wv*64 + g4*4;

  // --- prologue: gx for t=0 ---
  u16x4 cxA[3][4], cxB[3][4];
  #pragma unroll
  for (int gt = 0; gt < 3; ++gt)
    #pragma unroll
    for (int jt = 0; jt < 4; ++jt)
      cxA[gt][jt] = *(const u16x4*)(pg + gt*256 + jt*16);
  pg += dgx;

  __syncthreads();

// One GRU step. P = hbuf parity (compile-time), CX = this step's gate_x,
// NX = next step's gate_x (issued here, consumed next step -> HBM latency
// hides under a full step; barrier never drains vmcnt).
#define STEP(P, CX, NX)                                                       \
  {                                                                           \
    _Pragma("unroll") for (int gt = 0; gt < 3; ++gt)                          \
      _Pragma("unroll") for (int jt = 0; jt < 4; ++jt)                        \
        NX[gt][jt] = *(const u16x4*)(pg + gt*256 + jt*16);                    \
    f32x4 acc[12];                                                            \
    _Pragma("unroll") for (int rt = 0; rt < 8; ++rt) acc[rt] = (f32x4)0.0f;   \
    _Pragma("unroll") for (int jt = 0; jt < 4; ++jt)                          \
      acc[8+jt] = *(const f32x4*)&bnl[wv*64 + jt*16 + g4*4];                  \
    _Pragma("unroll") for (int kf = 0; kf < 8; ++kf) {                        \
      short8 b = *(const short8*)&hbuf[P][(kf*64 + lane)*8];                  \
      _Pragma("unroll") for (int rt = 0; rt < 8; ++rt)                        \
        MFMA_AG(acc[rt], aA[rt][kf], b);                                      \
      _Pragma("unroll") for (int jt = 0; jt < 4; ++jt)                        \
        MFMA_VG(acc[8+jt], aV[jt][kf], b);                                    \
    }                                                                         \
    _Pragma("unroll") for (int jt = 0; jt < 4; ++jt) {                        \
      u16x4 hold = *(const u16x4*)&hbuf[P][woff[jt]];                         \
      u16x4 hn;                                                               \
      _Pragma("unroll") for (int i = 0; i < 4; ++i) {                         \
        const float r = fast_sigm(bf2f(CX[0][jt][i]) + acc[jt][i]);           \
        const float z = fast_sigm(bf2f(CX[1][jt][i]) + acc[4+jt][i]);         \
        const float nn = fast_tanh(bf2f(CX[2][jt][i]) + r * acc[8+jt][i]);    \
        const float hf = nn + z * (bf2f(hold[i]) - nn);                       \
        hn[i] = f2bf(hf);                                                     \
      }                                                                       \
      *(u16x4*)&hbuf[P^1][woff[jt]] = hn;                                     \
      *(u16x4*)(pa + jt*16) = hn;                                             \
    }                                                                         \
    pg += dgx; pa += dac;                                                     \
    asm volatile("s_waitcnt lgkmcnt(0)\n\ts_barrier" ::: "memory");           \
  }

  #pragma unroll 1
  for (int t2 = 0; t2 < 256; ++t2) {
    STEP(0, cxA, cxB)
    STEP(1, cxB, cxA)
  }
#undef STEP

  // epilogue: final hidden state is in hbuf[0] (512 toggles)
  {
    float* po = hOut + ((long)(layer*2 + d)*BATCH + mb)*HID + wv*64 + g4*4;
    #pragma unroll
    for (int jt = 0; jt < 4; ++jt) {
      u16x4 hv = *(const u16x4*)&hbuf[0][woff[jt]];
      #pragma unroll
      for (int i = 0; i < 4; ++i) po[jt*16 + i] = bf2f(hv[i]);
    }
  }
}

extern "C" void kernel_launch(void* const* d_in, const int* in_sizes, int n_in,
                              void* d_out, int out_size, void* d_ws, size_t ws_size,
                              hipStream_t stream) {
  const float* x   = (const float*)d_in[0];
  const float* h0  = (const float*)d_in[1];
  const float* wih = (const float*)d_in[2];
  const float* whh = (const float*)d_in[3];
  const float* bih = (const float*)d_in[4];
  const float* bhh = (const float*)d_in[5];
  float* out = (float*)d_out;
  char* ws = (char*)d_ws;
  unsigned short* actA = (unsigned short*)ws;                    //  67,108,864 B
  unsigned short* actB = (unsigned short*)(ws + 67108864);       //  67,108,864 B
  unsigned short* gxb  = (unsigned short*)(ws + 134217728);      // 201,326,592 B
  unsigned short* wihb = (unsigned short*)(ws + 335544320);      //   4,718,592 B
  unsigned short* whhb = (unsigned short*)(ws + 340262912);      //   2,359,296 B
  if (ws_size < 342622208ULL) return;

  hipLaunchKernelGGL(cvt_bf16, dim3(2048), dim3(256), 0, stream, x,   actA, (long)33554432);
  hipLaunchKernelGGL(cvt_bf16, dim3(512),  dim3(256), 0, stream, wih, wihb, (long)2359296);
  hipLaunchKernelGGL(cvt_bf16, dim3(256),  dim3(256), 0, stream, whh, whhb, (long)1179648);

  for (int l = 0; l < 3; ++l) {
    const unsigned short* Ain = (l == 1) ? actB : actA;
    unsigned short* Aout      = (l == 1) ? actA : actB;
    hipLaunchKernelGGL(gemm_gx, dim3(6144), dim3(256), 0, stream,
                       Ain, wihb + (long)l*1536*512, bih + l*1536, bhh + l*1536, gxb);
    hipLaunchKernelGGL(gru_rec, dim3(16), dim3(256), 0, stream,
                       gxb, whhb + (long)l*2*768*256, bhh + l*1536, h0, Aout, out, l);
  }
}

// Round 10
// 3995.652 us; speedup vs baseline: 1.5258x; 1.0908x over previous
//
#include <hip/hip_runtime.h>
#include <stdint.h>

#define T_LEN 512
#define BATCH 128
#define HID 256
#define MROWS (T_LEN*BATCH)   // 65536
#define KIN 512

typedef __attribute__((ext_vector_type(8))) short short8;
typedef __attribute__((ext_vector_type(4))) float f32x4;
typedef __attribute__((ext_vector_type(4))) unsigned short u16x4;

static __device__ __forceinline__ float bf2f(unsigned short u) {
  union { unsigned int u; float f; } c; c.u = ((unsigned int)u) << 16; return c.f;
}
static __device__ __forceinline__ unsigned short f2bf(float f) {
  union { float f; unsigned int u; } c; c.f = f;
  unsigned int x = c.u;
  x += 0x7fffu + ((x >> 16) & 1u);   // RNE
  return (unsigned short)(x >> 16);
}
static __device__ __forceinline__ void gload_lds16(const void* g, void* l) {
  __builtin_amdgcn_global_load_lds((const __attribute__((address_space(1))) unsigned int*)g,
                                   (__attribute__((address_space(3))) unsigned int*)l,
                                   16, 0, 0);
}
static __device__ __forceinline__ float fast_sigm(float x) {
  return __builtin_amdgcn_rcpf(1.0f + __expf(-x));
}
static __device__ __forceinline__ float fast_tanh(float x) {
  float e = __expf(2.0f * x);
  return 1.0f - 2.0f * __builtin_amdgcn_rcpf(1.0f + e);
}

// MFMA with A-operand pinned to AGPR / in arch VGPR (both r5-proven).
#define MFMA_AG(D, W, B) \
  asm("v_mfma_f32_16x16x32_bf16 %0, %1, %2, %0" : "+v"(D) : "a"(W), "v"(B))
#define MFMA_VG(D, W, B) \
  asm("v_mfma_f32_16x16x32_bf16 %0, %1, %2, %0" : "+v"(D) : "v"(W), "v"(B))

// ---------------- fp32 -> bf16 conversion (n % 4 == 0) ----------------
__global__ void cvt_bf16(const float* __restrict__ in, unsigned short* __restrict__ out, long n) {
  long i = ((long)blockIdx.x * blockDim.x + threadIdx.x) * 4;
  const long stride = (long)gridDim.x * blockDim.x * 4;
  for (; i < n; i += stride) {
    f32x4 v = *(const f32x4*)(in + i);
    u16x4 o;
    o[0] = f2bf(v[0]); o[1] = f2bf(v[1]); o[2] = f2bf(v[2]); o[3] = f2bf(v[3]);
    *(u16x4*)(out + i) = o;
  }
}

// ---------------- input GEMM: gate_x = A[65536,512] * W[1536,512]^T + bias ----------------
__global__ __launch_bounds__(256) void gemm_gx(
    const unsigned short* __restrict__ A,
    const unsigned short* __restrict__ Bw,
    const float* __restrict__ bih,
    const float* __restrict__ bhh,
    unsigned short* __restrict__ gx)
{
  __shared__ unsigned short As[128*64];
  __shared__ unsigned short Bs[128*64];
  const int tid = threadIdx.x, lane = tid & 63, wv = tid >> 6;
  const int bid = blockIdx.x;
  const int nt = bid % 12; const long mt = bid / 12;
  const long m0 = mt * 128; const int n0 = nt * 128;
  const int wm = wv >> 1, wn = wv & 1;
  const int r8 = lane >> 3, c8 = lane & 7;

  f32x4 acc[4][4];
  #pragma unroll
  for (int i = 0; i < 4; ++i) {
    #pragma unroll
    for (int j = 0; j < 4; ++j) acc[i][j] = (f32x4)0.0f;
  }

  for (int kt = 0; kt < 8; ++kt) {
    const int kb = kt * 64;
    #pragma unroll
    for (int c = 0; c < 4; ++c) {
      const int rr = c*32 + wv*8;
      gload_lds16(A  + (m0 + rr + r8) * (long)KIN + kb + c8*8, &As[rr*64]);
      gload_lds16(Bw + (long)(n0 + rr + r8) * KIN + kb + c8*8, &Bs[rr*64]);
    }
    __syncthreads();
    #pragma unroll
    for (int kk = 0; kk < 2; ++kk) {
      short8 af[4], bfr[4];
      #pragma unroll
      for (int i = 0; i < 4; ++i)
        af[i] = *(const short8*)&As[(wm*64 + i*16 + (lane&15))*64 + kk*32 + (lane>>4)*8];
      #pragma unroll
      for (int j = 0; j < 4; ++j)
        bfr[j] = *(const short8*)&Bs[(wn*64 + j*16 + (lane&15))*64 + kk*32 + (lane>>4)*8];
      #pragma unroll
      for (int i = 0; i < 4; ++i) {
        #pragma unroll
        for (int j = 0; j < 4; ++j)
          acc[i][j] = __builtin_amdgcn_mfma_f32_16x16x32_bf16(af[i], bfr[j], acc[i][j], 0, 0, 0);
      }
    }
    __syncthreads();
  }

  const int d = (n0 >= 768) ? 1 : 0;
  #pragma unroll
  for (int j = 0; j < 4; ++j) {
    const int n = n0 + wn*64 + j*16 + (lane & 15);
    const int g = n - d*768;
    const float bias = bih[n] + ((g < 512) ? bhh[n] : 0.0f);
    #pragma unroll
    for (int i = 0; i < 4; ++i) {
      const long row = m0 + wm*64 + i*16 + (lane >> 4)*4;
      unsigned short* op = gx + ((long)d*MROWS + row)*768 + g;
      #pragma unroll
      for (int r = 0; r < 4; ++r)
        op[(long)r*768] = f2bf(acc[i][j][r] + bias);
    }
  }
}

// ---------------- recurrent scan: r5 core + gate_x staged via global_load_lds ----------------
// 16 WGs (dir = blk>>3, batch slice of 16 = blk&7), 256 threads (4 waves, 1/SIMD).
// EXACT r5 MFMA core (the only passing asm config): aA[8][8] in AGPR ("a"),
// aV[4][8] in VGPR, b-fragment loaded per-kf inside the loop, hold from
// hbuf[P], epilogue from hbuf[0]. Single change vs r5: the 48-VGPR cx/nx
// gate_x double-buffer is replaced by global_load_lds staging of the step's
// contiguous 24KB tile (6 issues/wave, LDS double-buffered, one step ahead).
// Per-lane SOURCE addresses are permuted (m173) so the linear LDS write lands
// as [col-block g8 = J>>3][row c] -> gate-phase reads are ~4-way-conflict-free.
// Frees ~48 arch VGPRs -> allocator slack (~216/256) -> less copy churn.
__global__ __launch_bounds__(256, 1) void gru_rec(
    const unsigned short* __restrict__ gx,    // [2][65536][768] bf16
    const unsigned short* __restrict__ Whh,   // [2][768][256] bf16 (this layer)
    const float* __restrict__ bhh,            // [2][768] fp32 (this layer)
    const float* __restrict__ h0,             // [6][128][256]
    unsigned short* __restrict__ act,         // [65536][512] bf16 (layer output)
    float* __restrict__ hOut,                 // d_out [6][128][256]
    const int layer)
{
  __shared__ unsigned short hbuf[2][4096];    // [buf][ (j>>3)*128 + col*8 + (j&7) ]
  __shared__ unsigned short gxl[2][12288];    // [buf][chunk I=g8*16+c][8 shorts]
  __shared__ float bnl[256];                  // n-gate b_hh for this dir
  const int tid = threadIdx.x, lane = tid & 63, wv = tid >> 6;  // wv 0..3
  const int d = blockIdx.x >> 3, s = blockIdx.x & 7;
  const int g4 = lane >> 4, c = lane & 15;
  const int mb = s*16 + c;

  const unsigned short* wb = Whh + (long)d*768*256;

  // --- stationary weights (r5 layout, verbatim) ---
  short8 aA[8][8];
  short8 aV[4][8];
  #pragma unroll
  for (int rt = 0; rt < 8; ++rt) {
    const int row = (rt>>2)*256 + wv*64 + (rt&3)*16 + c;
    #pragma unroll
    for (int kf = 0; kf < 8; ++kf)
      aA[rt][kf] = *(const short8*)&wb[row*256 + kf*32 + g4*8];
  }
  #pragma unroll
  for (int jt = 0; jt < 4; ++jt) {
    const int row = 512 + wv*64 + jt*16 + c;
    #pragma unroll
    for (int kf = 0; kf < 8; ++kf)
      aV[jt][kf] = *(const short8*)&wb[row*256 + kf*32 + g4*8];
  }

  bnl[tid] = bhh[d*768 + 512 + tid];

  // thread's own j-elems: j = wv*64 + jt*16 + g4*4 + i  (i=0..3), col = c
  int woff[4];
  #pragma unroll
  for (int jt = 0; jt < 4; ++jt)
    woff[jt] = (wv*8 + jt*2 + (g4>>1))*128 + c*8 + (g4&1)*4;

  // gate-phase gxl read base: chunk g8 = gt*32 + wv*8 + jt*2 + (g4>>1), row c.
  // short idx = (g8*16 + c)*8 + (g4&1)*4; jt adds 256, gt adds 4096.
  const int gA = ((wv*8 + (g4>>1))*16 + c)*8 + (g4&1)*4;

  // --- init h into hbuf[0] ---
  {
    const float* hp = h0 + ((long)(layer*2 + d)*BATCH + mb)*HID + wv*64 + g4*4;
    #pragma unroll
    for (int jt = 0; jt < 4; ++jt) {
      u16x4 hv;
      #pragma unroll
      for (int i = 0; i < 4; ++i) hv[i] = f2bf(hp[jt*16 + i]);
      *(u16x4*)&hbuf[0][woff[jt]] = hv;
    }
  }

  // --- running pointers ---
  const long t0 = d ? 511 : 0;
  const long dgx = d ? -(long)(BATCH*768) : (long)(BATCH*768);
  const long dac = d ? -(long)(BATCH*512) : (long)(BATCH*512);
  // staging source (m173 pre-permuted): chunk I = issue*256 + wv*64 + lane
  // maps to global row (I&15)=c, col-block (I>>4)*8 = (issue*16 + wv*4 + g4)*8.
  const unsigned short* sgbase = gx + ((long)d*MROWS + t0*BATCH + s*16 + c)*768 + (wv*4 + g4)*8;
  unsigned short* pa = act + (t0*BATCH + mb)*512 + d*256 + wv*64 + g4*4;

  // --- prologue: stage tile(t0) -> gxl[0] ---
  #pragma unroll
  for (int k = 0; k < 6; ++k)
    gload_lds16(sgbase + k*128, &gxl[0][k*2048 + wv*512]);
  sgbase += dgx;

  __syncthreads();   // full drain: weights, h0, bnl, stage(t0) visible

// One GRU step. P = hbuf/gxl parity (compile-time). Stage tile(t+1) first
// (consumed next step -> HBM latency hides under a full step); r5 MFMA core
// verbatim; gate phase reads gxl[P]; publish h to hbuf[P^1] + act.
#define STEP(P)                                                               \
  {                                                                           \
    _Pragma("unroll") for (int k = 0; k < 6; ++k)                             \
      gload_lds16(sgbase + k*128, &gxl[(P)^1][k*2048 + wv*512]);              \
    sgbase += dgx;                                                            \
    f32x4 acc[12];                                                            \
    _Pragma("unroll") for (int rt = 0; rt < 8; ++rt) acc[rt] = (f32x4)0.0f;   \
    _Pragma("unroll") for (int jt = 0; jt < 4; ++jt)                          \
      acc[8+jt] = *(const f32x4*)&bnl[wv*64 + jt*16 + g4*4];                  \
    _Pragma("unroll") for (int kf = 0; kf < 8; ++kf) {                        \
      short8 b = *(const short8*)&hbuf[P][(kf*64 + lane)*8];                  \
      MFMA_AG(acc[0], aA[0][kf], b); MFMA_AG(acc[1], aA[1][kf], b);           \
      MFMA_AG(acc[2], aA[2][kf], b); MFMA_AG(acc[3], aA[3][kf], b);           \
      MFMA_AG(acc[4], aA[4][kf], b); MFMA_AG(acc[5], aA[5][kf], b);           \
      MFMA_AG(acc[6], aA[6][kf], b); MFMA_AG(acc[7], aA[7][kf], b);           \
      MFMA_VG(acc[8],  aV[0][kf], b); MFMA_VG(acc[9],  aV[1][kf], b);         \
      MFMA_VG(acc[10], aV[2][kf], b); MFMA_VG(acc[11], aV[3][kf], b);         \
    }                                                                         \
    _Pragma("unroll") for (int jt = 0; jt < 4; ++jt) {                        \
      u16x4 xr = *(const u16x4*)&gxl[P][gA + jt*256];                         \
      u16x4 xz = *(const u16x4*)&gxl[P][gA + jt*256 + 4096];                  \
      u16x4 xn = *(const u16x4*)&gxl[P][gA + jt*256 + 8192];                  \
      u16x4 hold = *(const u16x4*)&hbuf[P][woff[jt]];                         \
      u16x4 hn;                                                               \
      _Pragma("unroll") for (int i = 0; i < 4; ++i) {                         \
        const float r = fast_sigm(bf2f(xr[i]) + acc[jt][i]);                  \
        const float z = fast_sigm(bf2f(xz[i]) + acc[4+jt][i]);                \
        const float nn = fast_tanh(bf2f(xn[i]) + r * acc[8+jt][i]);           \
        const float hf = nn + z * (bf2f(hold[i]) - nn);                       \
        hn[i] = f2bf(hf);                                                     \
      }                                                                       \
      *(u16x4*)&hbuf[(P)^1][woff[jt]] = hn;                                   \
      *(u16x4*)(pa + jt*16) = hn;                                             \
    }                                                                         \
    pa += dac;                                                                \
    asm volatile("s_waitcnt vmcnt(0) lgkmcnt(0)\n\ts_barrier" ::: "memory");  \
  }

  #pragma unroll 1
  for (int t2 = 0; t2 < 256; ++t2) {
    STEP(0)
    STEP(1)
  }
#undef STEP

  // epilogue: final hidden state is in hbuf[0] (512 toggles)
  {
    float* po = hOut + ((long)(layer*2 + d)*BATCH + mb)*HID + wv*64 + g4*4;
    #pragma unroll
    for (int jt = 0; jt < 4; ++jt) {
      u16x4 hv = *(const u16x4*)&hbuf[0][woff[jt]];
      #pragma unroll
      for (int i = 0; i < 4; ++i) po[jt*16 + i] = bf2f(hv[i]);
    }
  }
}

extern "C" void kernel_launch(void* const* d_in, const int* in_sizes, int n_in,
                              void* d_out, int out_size, void* d_ws, size_t ws_size,
                              hipStream_t stream) {
  const float* x   = (const float*)d_in[0];
  const float* h0  = (const float*)d_in[1];
  const float* wih = (const float*)d_in[2];
  const float* whh = (const float*)d_in[3];
  const float* bih = (const float*)d_in[4];
  const float* bhh = (const float*)d_in[5];
  float* out = (float*)d_out;
  char* ws = (char*)d_ws;
  unsigned short* actA = (unsigned short*)ws;                    //  67,108,864 B
  unsigned short* actB = (unsigned short*)(ws + 67108864);       //  67,108,864 B
  unsigned short* gxb  = (unsigned short*)(ws + 134217728);      // 201,326,592 B
  unsigned short* wihb = (unsigned short*)(ws + 335544320);      //   4,718,592 B
  unsigned short* whhb = (unsigned short*)(ws + 340262912);      //   2,359,296 B
  if (ws_size < 342622208ULL) return;

  hipLaunchKernelGGL(cvt_bf16, dim3(2048), dim3(256), 0, stream, x,   actA, (long)33554432);
  hipLaunchKernelGGL(cvt_bf16, dim3(512),  dim3(256), 0, stream, wih, wihb, (long)2359296);
  hipLaunchKernelGGL(cvt_bf16, dim3(256),  dim3(256), 0, stream, whh, whhb, (long)1179648);

  for (int l = 0; l < 3; ++l) {
    const unsigned short* Ain = (l == 1) ? actB : actA;
    unsigned short* Aout      = (l == 1) ? actA : actB;
    hipLaunchKernelGGL(gemm_gx, dim3(6144), dim3(256), 0, stream,
                       Ain, wihb + (long)l*1536*512, bih + l*1536, bhh + l*1536, gxb);
    hipLaunchKernelGGL(gru_rec, dim3(16), dim3(256), 0, stream,
                       gxb, whhb + (long)l*2*768*256, bhh + l*1536, h0, Aout, out, l);
  }
}

// Round 13
// 3793.304 us; speedup vs baseline: 1.6072x; 1.0533x over previous
//
#include <hip/hip_runtime.h>
#include <stdint.h>

#define T_LEN 512
#define BATCH 128
#define HID 256
#define MROWS (T_LEN*BATCH)   // 65536
#define KIN 512

typedef __attribute__((ext_vector_type(8))) short short8;
typedef __attribute__((ext_vector_type(4))) float f32x4;
typedef __attribute__((ext_vector_type(4))) unsigned short u16x4;

static __device__ __forceinline__ float bf2f(unsigned short u) {
  union { unsigned int u; float f; } c; c.u = ((unsigned int)u) << 16; return c.f;
}
static __device__ __forceinline__ unsigned short f2bf(float f) {
  union { float f; unsigned int u; } c; c.f = f;
  unsigned int x = c.u;
  x += 0x7fffu + ((x >> 16) & 1u);   // RNE
  return (unsigned short)(x >> 16);
}
static __device__ __forceinline__ void gload_lds16(const void* g, void* l) {
  __builtin_amdgcn_global_load_lds((const __attribute__((address_space(1))) unsigned int*)g,
                                   (__attribute__((address_space(3))) unsigned int*)l,
                                   16, 0, 0);
}
static __device__ __forceinline__ float fast_sigm(float x) {
  return __builtin_amdgcn_rcpf(1.0f + __expf(-x));
}
static __device__ __forceinline__ float fast_tanh(float x) {
  float e = __expf(2.0f * x);
  return 1.0f - 2.0f * __builtin_amdgcn_rcpf(1.0f + e);
}

// MFMA with A-operand pinned to AGPR / in arch VGPR (both r5/r10-proven).
#define MFMA_AG(D, W, B) \
  asm("v_mfma_f32_16x16x32_bf16 %0, %1, %2, %0" : "+v"(D) : "a"(W), "v"(B))
#define MFMA_VG(D, W, B) \
  asm("v_mfma_f32_16x16x32_bf16 %0, %1, %2, %0" : "+v"(D) : "v"(W), "v"(B))

// ---------------- fp32 -> bf16 conversion (n % 4 == 0) ----------------
__global__ void cvt_bf16(const float* __restrict__ in, unsigned short* __restrict__ out, long n) {
  long i = ((long)blockIdx.x * blockDim.x + threadIdx.x) * 4;
  const long stride = (long)gridDim.x * blockDim.x * 4;
  for (; i < n; i += stride) {
    f32x4 v = *(const f32x4*)(in + i);
    u16x4 o;
    o[0] = f2bf(v[0]); o[1] = f2bf(v[1]); o[2] = f2bf(v[2]); o[3] = f2bf(v[3]);
    *(u16x4*)(out + i) = o;
  }
}

// ---------------- input GEMM: gate_x = A[65536,512] * W[1536,512]^T + bias ----------------
__global__ __launch_bounds__(256) void gemm_gx(
    const unsigned short* __restrict__ A,
    const unsigned short* __restrict__ Bw,
    const float* __restrict__ bih,
    const float* __restrict__ bhh,
    unsigned short* __restrict__ gx)
{
  __shared__ unsigned short As[128*64];
  __shared__ unsigned short Bs[128*64];
  const int tid = threadIdx.x, lane = tid & 63, wv = tid >> 6;
  const int bid = blockIdx.x;
  const int nt = bid % 12; const long mt = bid / 12;
  const long m0 = mt * 128; const int n0 = nt * 128;
  const int wm = wv >> 1, wn = wv & 1;
  const int r8 = lane >> 3, c8 = lane & 7;

  f32x4 acc[4][4];
  #pragma unroll
  for (int i = 0; i < 4; ++i) {
    #pragma unroll
    for (int j = 0; j < 4; ++j) acc[i][j] = (f32x4)0.0f;
  }

  for (int kt = 0; kt < 8; ++kt) {
    const int kb = kt * 64;
    #pragma unroll
    for (int c = 0; c < 4; ++c) {
      const int rr = c*32 + wv*8;
      gload_lds16(A  + (m0 + rr + r8) * (long)KIN + kb + c8*8, &As[rr*64]);
      gload_lds16(Bw + (long)(n0 + rr + r8) * KIN + kb + c8*8, &Bs[rr*64]);
    }
    __syncthreads();
    #pragma unroll
    for (int kk = 0; kk < 2; ++kk) {
      short8 af[4], bfr[4];
      #pragma unroll
      for (int i = 0; i < 4; ++i)
        af[i] = *(const short8*)&As[(wm*64 + i*16 + (lane&15))*64 + kk*32 + (lane>>4)*8];
      #pragma unroll
      for (int j = 0; j < 4; ++j)
        bfr[j] = *(const short8*)&Bs[(wn*64 + j*16 + (lane&15))*64 + kk*32 + (lane>>4)*8];
      #pragma unroll
      for (int i = 0; i < 4; ++i) {
        #pragma unroll
        for (int j = 0; j < 4; ++j)
          acc[i][j] = __builtin_amdgcn_mfma_f32_16x16x32_bf16(af[i], bfr[j], acc[i][j], 0, 0, 0);
      }
    }
    __syncthreads();
  }

  const int d = (n0 >= 768) ? 1 : 0;
  #pragma unroll
  for (int j = 0; j < 4; ++j) {
    const int n = n0 + wn*64 + j*16 + (lane & 15);
    const int g = n - d*768;
    const float bias = bih[n] + ((g < 512) ? bhh[n] : 0.0f);
    #pragma unroll
    for (int i = 0; i < 4; ++i) {
      const long row = m0 + wm*64 + i*16 + (lane >> 4)*4;
      unsigned short* op = gx + ((long)d*MROWS + row)*768 + g;
      #pragma unroll
      for (int r = 0; r < 4; ++r)
        op[(long)r*768] = f2bf(acc[i][j][r] + bias);
    }
  }
}

// ---------------- recurrent scan: r10 structure verbatim + counted vmcnt ----------------
// 16 WGs (dir = blk>>3, batch slice of 16 = blk&7), 256 threads (4 waves, 1/SIMD).
// r10 (the passing 3995us kernel) with ONE mechanical change: the end-of-step
// wait is vmcnt(4) instead of vmcnt(0). The 4 newest VMEM ops at that point
// are this step's act stores (issued at the bottom); everything older -- the
// 6 global_load_lds staged at the step top -- must and does drain. vmcnt
// retires in issue order (m135), so vmcnt(4) guarantees gxl[P^1] is resident
// before the barrier while letting the act stores float a full step instead
// of putting an HBM store round-trip on the serial critical path x1536 steps.
// act is consumed only by the next kernel launch (completion guaranteed).
__global__ __launch_bounds__(256, 1) void gru_rec(
    const unsigned short* __restrict__ gx,    // [2][65536][768] bf16
    const unsigned short* __restrict__ Whh,   // [2][768][256] bf16 (this layer)
    const float* __restrict__ bhh,            // [2][768] fp32 (this layer)
    const float* __restrict__ h0,             // [6][128][256]
    unsigned short* __restrict__ act,         // [65536][512] bf16 (layer output)
    float* __restrict__ hOut,                 // d_out [6][128][256]
    const int layer)
{
  __shared__ unsigned short hbuf[2][4096];    // [buf][ (j>>3)*128 + col*8 + (j&7) ]
  __shared__ unsigned short gxl[2][12288];    // [buf][chunk I=g8*16+c][8 shorts]
  __shared__ float bnl[256];                  // n-gate b_hh for this dir
  const int tid = threadIdx.x, lane = tid & 63, wv = tid >> 6;  // wv 0..3
  const int d = blockIdx.x >> 3, s = blockIdx.x & 7;
  const int g4 = lane >> 4, c = lane & 15;
  const int mb = s*16 + c;

  const unsigned short* wb = Whh + (long)d*768*256;

  // --- stationary weights (r5/r10 layout, verbatim) ---
  short8 aA[8][8];   // rt = gate*4+jt, gate 0=r,1=z -> AGPR (256)
  short8 aV[4][8];   // n-gate -> VGPR (128)
  #pragma unroll
  for (int rt = 0; rt < 8; ++rt) {
    const int row = (rt>>2)*256 + wv*64 + (rt&3)*16 + c;
    #pragma unroll
    for (int kf = 0; kf < 8; ++kf)
      aA[rt][kf] = *(const short8*)&wb[row*256 + kf*32 + g4*8];
  }
  #pragma unroll
  for (int jt = 0; jt < 4; ++jt) {
    const int row = 512 + wv*64 + jt*16 + c;
    #pragma unroll
    for (int kf = 0; kf < 8; ++kf)
      aV[jt][kf] = *(const short8*)&wb[row*256 + kf*32 + g4*8];
  }

  bnl[tid] = bhh[d*768 + 512 + tid];

  // thread's own j-elems: j = wv*64 + jt*16 + g4*4 + i  (i=0..3), col = c
  int woff[4];
  #pragma unroll
  for (int jt = 0; jt < 4; ++jt)
    woff[jt] = (wv*8 + jt*2 + (g4>>1))*128 + c*8 + (g4&1)*4;

  // gate-phase gxl read base (r10-proven layout/permutation)
  const int gA = ((wv*8 + (g4>>1))*16 + c)*8 + (g4&1)*4;

  // --- init h into hbuf[0] ---
  {
    const float* hp = h0 + ((long)(layer*2 + d)*BATCH + mb)*HID + wv*64 + g4*4;
    #pragma unroll
    for (int jt = 0; jt < 4; ++jt) {
      u16x4 hv;
      #pragma unroll
      for (int i = 0; i < 4; ++i) hv[i] = f2bf(hp[jt*16 + i]);
      *(u16x4*)&hbuf[0][woff[jt]] = hv;
    }
  }

  // --- running pointers ---
  const long t0 = d ? 511 : 0;
  const long dgx = d ? -(long)(BATCH*768) : (long)(BATCH*768);
  const long dac = d ? -(long)(BATCH*512) : (long)(BATCH*512);
  const unsigned short* sgbase = gx + ((long)d*MROWS + t0*BATCH + s*16 + c)*768 + (wv*4 + g4)*8;
  unsigned short* pa = act + (t0*BATCH + mb)*512 + d*256 + wv*64 + g4*4;

  // --- prologue: stage tile(t0) -> gxl[0] ---
  #pragma unroll
  for (int k = 0; k < 6; ++k)
    gload_lds16(sgbase + k*128, &gxl[0][k*2048 + wv*512]);
  sgbase += dgx;

  __syncthreads();   // full drain: weights, h0, bnl, stage(t0) visible

// One GRU step. P = hbuf/gxl parity (compile-time). Stage tile(t+1) first
// (consumed next step -> HBM latency hides under a full step); r10 MFMA core
// verbatim; gate phase reads gxl[P]; publish h to hbuf[P^1] + act.
// End-of-step wait: vmcnt(4) = drain the 6 staging loads (older), float the
// 4 act stores (newest); lgkmcnt(0) for hbuf ds_write visibility.
#define STEP(P)                                                               \
  {                                                                           \
    _Pragma("unroll") for (int k = 0; k < 6; ++k)                             \
      gload_lds16(sgbase + k*128, &gxl[(P)^1][k*2048 + wv*512]);              \
    sgbase += dgx;                                                            \
    f32x4 acc[12];                                                            \
    _Pragma("unroll") for (int rt = 0; rt < 8; ++rt) acc[rt] = (f32x4)0.0f;   \
    _Pragma("unroll") for (int jt = 0; jt < 4; ++jt)                          \
      acc[8+jt] = *(const f32x4*)&bnl[wv*64 + jt*16 + g4*4];                  \
    _Pragma("unroll") for (int kf = 0; kf < 8; ++kf) {                        \
      short8 b = *(const short8*)&hbuf[P][(kf*64 + lane)*8];                  \
      MFMA_AG(acc[0], aA[0][kf], b); MFMA_AG(acc[1], aA[1][kf], b);           \
      MFMA_AG(acc[2], aA[2][kf], b); MFMA_AG(acc[3], aA[3][kf], b);           \
      MFMA_AG(acc[4], aA[4][kf], b); MFMA_AG(acc[5], aA[5][kf], b);           \
      MFMA_AG(acc[6], aA[6][kf], b); MFMA_AG(acc[7], aA[7][kf], b);           \
      MFMA_VG(acc[8],  aV[0][kf], b); MFMA_VG(acc[9],  aV[1][kf], b);         \
      MFMA_VG(acc[10], aV[2][kf], b); MFMA_VG(acc[11], aV[3][kf], b);         \
    }                                                                         \
    _Pragma("unroll") for (int jt = 0; jt < 4; ++jt) {                        \
      u16x4 xr = *(const u16x4*)&gxl[P][gA + jt*256];                         \
      u16x4 xz = *(const u16x4*)&gxl[P][gA + jt*256 + 4096];                  \
      u16x4 xn = *(const u16x4*)&gxl[P][gA + jt*256 + 8192];                  \
      u16x4 hold = *(const u16x4*)&hbuf[P][woff[jt]];                         \
      u16x4 hn;                                                               \
      _Pragma("unroll") for (int i = 0; i < 4; ++i) {                         \
        const float r = fast_sigm(bf2f(xr[i]) + acc[jt][i]);                  \
        const float z = fast_sigm(bf2f(xz[i]) + acc[4+jt][i]);                \
        const float nn = fast_tanh(bf2f(xn[i]) + r * acc[8+jt][i]);           \
        const float hf = nn + z * (bf2f(hold[i]) - nn);                       \
        hn[i] = f2bf(hf);                                                     \
      }                                                                       \
      *(u16x4*)&hbuf[(P)^1][woff[jt]] = hn;                                   \
      *(u16x4*)(pa + jt*16) = hn;                                             \
    }                                                                         \
    pa += dac;                                                                \
    asm volatile("s_waitcnt vmcnt(4) lgkmcnt(0)\n\ts_barrier" ::: "memory");  \
  }

  #pragma unroll 1
  for (int t2 = 0; t2 < 256; ++t2) {
    STEP(0)
    STEP(1)
  }
#undef STEP

  // epilogue: final hidden state is in hbuf[0] (512 toggles)
  {
    float* po = hOut + ((long)(layer*2 + d)*BATCH + mb)*HID + wv*64 + g4*4;
    #pragma unroll
    for (int jt = 0; jt < 4; ++jt) {
      u16x4 hv = *(const u16x4*)&hbuf[0][woff[jt]];
      #pragma unroll
      for (int i = 0; i < 4; ++i) po[jt*16 + i] = bf2f(hv[i]);
    }
  }
}

extern "C" void kernel_launch(void* const* d_in, const int* in_sizes, int n_in,
                              void* d_out, int out_size, void* d_ws, size_t ws_size,
                              hipStream_t stream) {
  const float* x   = (const float*)d_in[0];
  const float* h0  = (const float*)d_in[1];
  const float* wih = (const float*)d_in[2];
  const float* whh = (const float*)d_in[3];
  const float* bih = (const float*)d_in[4];
  const float* bhh = (const float*)d_in[5];
  float* out = (float*)d_out;
  char* ws = (char*)d_ws;
  unsigned short* actA = (unsigned short*)ws;                    //  67,108,864 B
  unsigned short* actB = (unsigned short*)(ws + 67108864);       //  67,108,864 B
  unsigned short* gxb  = (unsigned short*)(ws + 134217728);      // 201,326,592 B
  unsigned short* wihb = (unsigned short*)(ws + 335544320);      //   4,718,592 B
  unsigned short* whhb = (unsigned short*)(ws + 340262912);      //   2,359,296 B
  if (ws_size < 342622208ULL) return;

  hipLaunchKernelGGL(cvt_bf16, dim3(2048), dim3(256), 0, stream, x,   actA, (long)33554432);
  hipLaunchKernelGGL(cvt_bf16, dim3(512),  dim3(256), 0, stream, wih, wihb, (long)2359296);
  hipLaunchKernelGGL(cvt_bf16, dim3(256),  dim3(256), 0, stream, whh, whhb, (long)1179648);

  for (int l = 0; l < 3; ++l) {
    const unsigned short* Ain = (l == 1) ? actB : actA;
    unsigned short* Aout      = (l == 1) ? actA : actB;
    hipLaunchKernelGGL(gemm_gx, dim3(6144), dim3(256), 0, stream,
                       Ain, wihb + (long)l*1536*512, bih + l*1536, bhh + l*1536, gxb);
    hipLaunchKernelGGL(gru_rec, dim3(16), dim3(256), 0, stream,
                       gxb, whhb + (long)l*2*768*256, bhh + l*1536, h0, Aout, out, l);
  }
}